// Round 7
// baseline (2158.237 us; speedup 1.0000x reference)
//
#include <hip/hip_runtime.h>
#include <hip/hip_bf16.h>

// CustomLSTMModel: emb(32000x300 fp32, pad_idx=0) -> LSTM(300->512, 512 steps, B=256, fp32)
//                  -> FC(512->7, fp32). tokens int32; out fp32 [256,7].
// Internal: bf16 MFMA (RNE), fp32 accum/c/biases/FC. absmax ~1e-3 (R2/R4/R5/R6: 9.8e-4).
//
// R7 changes vs R6 (2.13 ms; publish path = 2 barriers + LDS bounce + all-wave drain):
//  - PER-WAVE flags (128/group): wave wv of block ib owns unit column chunk
//    {U0+4wv..U0+4wv+3} = one u64 per batch row. After ITS hh-MFMA+elementwise it
//    shfl-packs 32 u64s, issues bypassing stores, drains OWN stores (s_waitcnt vmcnt(0))
//    and publishes flags[g*128+ib*8+wv] — no cross-wave barrier before publish.
//  - Barriers 5 -> 3 (S2a poll-release, S2b h-staged, loop-end = x-staged).
//  - LDS bounce (h_scr) eliminated via 8 x __shfl pack.
//  - x-consume moved after hh-MFMA (x region free there); x-prefetch issued AFTER the
//    explicit vmcnt(0) so the drain never catches fresh HBM loads (R6 lesson preserved).
// Carried: no fences (relaxed agent atomics, LLC-coherent, no wbl2/inv); W+c in VGPRs;
// 8 groups x 16 blocks x 512 thr; wave0-only poll (u64 over 2 flags/lane); group=bid&7.

typedef unsigned short ushort_t;
typedef unsigned long long u64_t;
typedef __bf16 bf16x8 __attribute__((ext_vector_type(8)));
typedef unsigned short u16x8v __attribute__((ext_vector_type(8)));
typedef float f32x4 __attribute__((ext_vector_type(4)));

#define U_STRIDE 840   // ushorts: 320 (x incl zero pad) + 512 (h) + 8 pad; row = 1680B
#define HOFF 320

__device__ __forceinline__ float sigmoidf_(float x) { return 1.0f / (1.0f + __expf(-x)); }
__device__ __forceinline__ float tanhf_(float x)    { return 1.0f - 2.0f / (__expf(2.0f * x) + 1.0f); }

__device__ __forceinline__ ushort_t f2bf(float f) {   // RNE; inputs finite
    unsigned u = __builtin_bit_cast(unsigned, f);
    unsigned r = (u + 0x7FFFu + ((u >> 16) & 1u)) >> 16;
    return (ushort_t)r;
}
__device__ __forceinline__ float bf2f(ushort_t u) {
    unsigned v = ((unsigned)u) << 16;
    return __builtin_bit_cast(float, v);
}

// LLC-coherent (cache-bypassing) accessors — relaxed agent atomics, no fences.
__device__ __forceinline__ u64_t g_load64(const u64_t* p) {
    return __hip_atomic_load(p, __ATOMIC_RELAXED, __HIP_MEMORY_SCOPE_AGENT);
}
__device__ __forceinline__ void g_store64(u64_t* p, u64_t v) {
    __hip_atomic_store(p, v, __ATOMIC_RELAXED, __HIP_MEMORY_SCOPE_AGENT);
}
__device__ __forceinline__ void g_store_flag(int* p, int v) {
    __hip_atomic_store(p, v, __ATOMIC_RELAXED, __HIP_MEMORY_SCOPE_AGENT);
}

__global__ __launch_bounds__(512, 2)
void lstm_fused_kernel(const int* __restrict__ tokens,    // [256][512]
                       const float* __restrict__ emb,     // [32000][300]
                       const float* __restrict__ Wih,     // [2048][300]
                       const float* __restrict__ bih,     // [2048]
                       const float* __restrict__ Whh,     // [2048][512]
                       const float* __restrict__ bhh,     // [2048]
                       const float* __restrict__ Wfc,     // [7][512]
                       const float* __restrict__ bfc,     // [7]
                       float* __restrict__ out,           // [256][7]
                       int* __restrict__ flags,           // [1024] per-wave
                       ushort_t* __restrict__ hbuf)       // [2][256][512] bf16
{
    __shared__ ushort_t u_lds[32 * U_STRIDE];   // 53760 B

    const int tid = threadIdx.x;
    const int bid = blockIdx.x;
    const int g   = bid & 7;       // batch group 0..7 (XCD-aligned: round-robin dispatch)
    const int ib  = bid >> 3;      // block-in-group 0..15 -> unit slice
    const int Bg0 = g * 32;
    const int U0  = ib * 32;       // 32 units per block
    const int lane = tid & 63;
    const int wv   = tid >> 6;     // wave 0..7; owns unit columns U0+4wv..U0+4wv+3
    const int lm   = lane & 15;
    const int q    = lane >> 4;

    // ---- preload A-fragments, fp32 -> bf16 RNE (once) ----
    bf16x8 aih[10];
    bf16x8 ahh[16];
    {
        const int rp   = 16 * wv + lm;          // row in block's 128 (unit_local*4 + gate)
        const int gi   = rp & 3;
        const int up   = rp >> 2;               // unit_local 0..31
        const int grow = gi * 512 + U0 + up;    // global gate row (i,f,g,o blocks of 512)
#pragma unroll
        for (int kc = 0; kc < 10; ++kc) {
            u16x8v tmp;
#pragma unroll
            for (int j = 0; j < 8; ++j) {
                int col = 32 * kc + 8 * q + j;
                tmp[j] = (col < 300) ? f2bf(Wih[grow * 300 + col]) : (ushort_t)0;
            }
            aih[kc] = __builtin_bit_cast(bf16x8, tmp);
        }
#pragma unroll
        for (int kc = 0; kc < 16; ++kc) {
            u16x8v tmp;
#pragma unroll
            for (int j = 0; j < 8; ++j) {
                int col = 32 * kc + 8 * q + j;
                tmp[j] = f2bf(Whh[grow * 512 + col]);
            }
            ahh[kc] = __builtin_bit_cast(bf16x8, tmp);
        }
    }

    // ---- per-lane biases (fp32): unit = U0 + 4*wv + q; acc regs = i,f,g,o ----
    float bias0, bias1, bias2, bias3;
    {
        const int unit = U0 + 4 * wv + q;
        bias0 = bih[0 * 512 + unit] + bhh[0 * 512 + unit];
        bias1 = bih[1 * 512 + unit] + bhh[1 * 512 + unit];
        bias2 = bih[2 * 512 + unit] + bhh[2 * 512 + unit];
        bias3 = bih[3 * 512 + unit] + bhh[3 * 512 + unit];
    }

    // ---- init: zero our unit-slice of h parity-0 (h0=0), publish wave flags = 1 ----
    if (tid < 256) {
        int r = tid >> 3;        // batch row 0..31
        int d = tid & 7;         // 8 u64 = 32 units
        g_store64((u64_t*)(hbuf + (size_t)(Bg0 + r) * 512 + U0 + 4 * d), 0ull);
    }
    __syncthreads();             // drains all init stores
    if (tid < 8) g_store_flag(&flags[g * 128 + ib * 8 + tid], 1);

    // poll source: lane l checks flags[g*128 + 2l .. 2l+1] (one u64 atomic load)
    const u64_t* fl2 = (const u64_t*)&flags[g * 128 + 2 * lane];
    int* myflagp = &flags[g * 128 + ib * 8 + wv];

    float cA = 0.0f, cB = 0.0f;

    // ---- x prefetch state: thread handles row xr, elements xln+16k ----
    const int xr  = tid >> 4;        // batch row 0..31
    const int xln = tid & 15;
    const int xb  = Bg0 + xr;
    int tok_cur;                     // token whose emb row currently sits in xp
    int tok_nxt;
    float2 xp[10];
    {
        // stage x_0 directly, then prefetch x_1 into xp
        int tk0 = tokens[xb * 512 + 0];
        const float2* s2 = (const float2*)(emb + (size_t)tk0 * 300);
        unsigned int* dstx = (unsigned int*)(u_lds + xr * U_STRIDE);
        const bool tz = (tk0 != 0);
#pragma unroll
        for (int k = 0; k < 10; ++k) {
            int i = xln + 16 * k;
            unsigned int v = 0u;
            if (tz && i < 150) {
                float2 p = s2[i];
                v = (unsigned int)f2bf(p.x) | ((unsigned int)f2bf(p.y) << 16);
            }
            dstx[i] = v;
        }
        tok_cur = tokens[xb * 512 + 1];
        const float2* s2n = (const float2*)(emb + (size_t)tok_cur * 300);
#pragma unroll
        for (int k = 0; k < 10; ++k) {
            int i = xln + 16 * k;
            if (i < 150) xp[k] = s2n[i];
        }
        tok_nxt = tokens[xb * 512 + 2];
    }
    __syncthreads();   // x_0 staged

    for (int t = 0; t < 512; ++t) {
        // ---- 1. ih-MFMAs (x_t staged last iteration) ----
        f32x4 acc0 = {0.f, 0.f, 0.f, 0.f};
        f32x4 acc1 = {0.f, 0.f, 0.f, 0.f};
        const ushort_t* u0 = u_lds + lm * U_STRIDE + 8 * q;          // batches Bg0+0..15
        const ushort_t* u1 = u_lds + (16 + lm) * U_STRIDE + 8 * q;   // batches Bg0+16..31
#pragma unroll
        for (int kc = 0; kc < 10; ++kc) {
            bf16x8 b0 = __builtin_bit_cast(bf16x8, *(const u16x8v*)(u0 + 32 * kc));
            bf16x8 b1 = __builtin_bit_cast(bf16x8, *(const u16x8v*)(u1 + 32 * kc));
            acc0 = __builtin_amdgcn_mfma_f32_16x16x32_bf16(aih[kc], b0, acc0, 0, 0, 0);
            acc1 = __builtin_amdgcn_mfma_f32_16x16x32_bf16(aih[kc], b1, acc1, 0, 0, 0);
        }

        // ---- 2. wave 0 polls all 128 wave-flags (monotonic; poison<0 safe) ----
        if (wv == 0) {
            const int target = t + 1;
            while (true) {
                u64_t v2 = g_load64(fl2);
                int lo = (int)(unsigned)(v2 & 0xffffffffull);
                int hi = (int)(unsigned)(v2 >> 32);
                if (__all(lo >= target && hi >= target)) break;
                __builtin_amdgcn_s_sleep(1);
            }
            asm volatile("" ::: "memory");
        }
        __syncthreads();   // S2a: release all waves

        // ---- 3. stage h_t via bypassing u64 loads -> LDS (128 u64 per row) ----
        {
            const u64_t* hsrc = (const u64_t*)(hbuf + (size_t)(t & 1) * (256 * 512)
                                               + (size_t)xb * 512);
            u64_t* dsth = (u64_t*)(u_lds + xr * U_STRIDE + HOFF);
            u64_t tmp[8];
#pragma unroll
            for (int k = 0; k < 8; ++k) tmp[k] = g_load64(hsrc + xln + 16 * k);
#pragma unroll
            for (int k = 0; k < 8; ++k) dsth[xln + 16 * k] = tmp[k];
        }
        __syncthreads();   // S2b: h staged

        // ---- 4. hh-MFMAs ----
#pragma unroll
        for (int kc = 0; kc < 16; ++kc) {
            bf16x8 b0 = __builtin_bit_cast(bf16x8, *(const u16x8v*)(u0 + HOFF + 32 * kc));
            bf16x8 b1 = __builtin_bit_cast(bf16x8, *(const u16x8v*)(u1 + HOFF + 32 * kc));
            acc0 = __builtin_amdgcn_mfma_f32_16x16x32_bf16(ahh[kc], b0, acc0, 0, 0, 0);
            acc1 = __builtin_amdgcn_mfma_f32_16x16x32_bf16(ahh[kc], b1, acc1, 0, 0, 0);
        }

        // ---- 5. elementwise LSTM + shfl-pack + per-wave bypassing h stores ----
        {
            float ig = sigmoidf_(acc0.x + bias0);
            float fg = sigmoidf_(acc0.y + bias1);
            float gg = tanhf_(acc0.z + bias2);
            float og = sigmoidf_(acc0.w + bias3);
            cA = fg * cA + ig * gg;
            unsigned pA = f2bf(og * tanhf_(cA));

            ig = sigmoidf_(acc1.x + bias0);
            fg = sigmoidf_(acc1.y + bias1);
            gg = tanhf_(acc1.z + bias2);
            og = sigmoidf_(acc1.w + bias3);
            cB = fg * cB + ig * gg;
            unsigned pB = f2bf(og * tanhf_(cB));

            // gather q=0..3 halves for row lm (A: rows 0..15, B: rows 16..31)
            unsigned a0 = (unsigned)__shfl((int)pA, lm);
            unsigned a1 = (unsigned)__shfl((int)pA, lm + 16);
            unsigned a2 = (unsigned)__shfl((int)pA, lm + 32);
            unsigned a3 = (unsigned)__shfl((int)pA, lm + 48);
            unsigned b0 = (unsigned)__shfl((int)pB, lm);
            unsigned b1 = (unsigned)__shfl((int)pB, lm + 16);
            unsigned b2 = (unsigned)__shfl((int)pB, lm + 32);
            unsigned b3 = (unsigned)__shfl((int)pB, lm + 48);
            u64_t uA = (u64_t)(a0 | (a1 << 16)) | ((u64_t)(a2 | (a3 << 16)) << 32);
            u64_t uB = (u64_t)(b0 | (b1 << 16)) | ((u64_t)(b2 | (b3 << 16)) << 32);

            ushort_t* hdst = hbuf + (size_t)((t + 1) & 1) * (256 * 512);
            if (q == 0)
                g_store64((u64_t*)(hdst + (size_t)(Bg0 + lm) * 512 + U0 + 4 * wv), uA);
            else if (q == 1)
                g_store64((u64_t*)(hdst + (size_t)(Bg0 + 16 + lm) * 512 + U0 + 4 * wv), uB);
        }

        // ---- 6. consume xp -> LDS x_{t+1} (LDS only; doesn't touch vmcnt) ----
        {
            unsigned int* dstx = (unsigned int*)(u_lds + xr * U_STRIDE);
            const bool tz = (tok_cur != 0);
#pragma unroll
            for (int k = 0; k < 10; ++k) {
                int i = xln + 16 * k;
                unsigned int v = 0u;
                if (tz && i < 150)
                    v = (unsigned int)f2bf(xp[k].x) | ((unsigned int)f2bf(xp[k].y) << 16);
                dstx[i] = v;
            }
        }

        // ---- 7. drain OWN h stores, publish this wave's flag ----
        asm volatile("s_waitcnt vmcnt(0)" ::: "memory");
        if (lane == 0) g_store_flag(myflagp, t + 2);

        // ---- 8. issue x prefetch for t+2 (after the drain: stays in flight) ----
        {
            tok_cur = tok_nxt;
            const float2* s2 = (const float2*)(emb + (size_t)tok_cur * 300);
#pragma unroll
            for (int k = 0; k < 10; ++k) {
                int i = xln + 16 * k;
                if (i < 150) xp[k] = s2[i];
            }
            int t3 = (t + 3 < 512) ? (t + 3) : 511;
            tok_nxt = tokens[xb * 512 + t3];
        }
        __syncthreads();   // loop-end: x_{t+1} staged, h region free
    }

    // ---- wait group done (513), then FC: block handles batches Bg0+2*ib, +1 ----
    if (wv == 0) {
        while (true) {
            u64_t v2 = g_load64(fl2);
            int lo = (int)(unsigned)(v2 & 0xffffffffull);
            int hi = (int)(unsigned)(v2 >> 32);
            if (__all(lo >= 513 && hi >= 513)) break;
            __builtin_amdgcn_s_sleep(1);
        }
        asm volatile("" ::: "memory");
    }
    __syncthreads();

    {
        const int bb = Bg0 + 2 * ib + (wv & 1);
        const int obase = wv >> 1;                       // 0..3
        const ushort_t* hrow = hbuf + (size_t)bb * 512;  // final h in parity 0
        u64_t h0 = g_load64((const u64_t*)(hrow + lane * 8));
        u64_t h1 = g_load64((const u64_t*)(hrow + lane * 8 + 4));
        float hv[8];
#pragma unroll
        for (int j = 0; j < 4; ++j) hv[j]     = bf2f((ushort_t)(h0 >> (16 * j)));
#pragma unroll
        for (int j = 0; j < 4; ++j) hv[4 + j] = bf2f((ushort_t)(h1 >> (16 * j)));
#pragma unroll
        for (int oo = 0; oo < 2; ++oo) {
            int o = obase + oo * 4;
            if (o < 7) {
                f32x4 w0 = *(const f32x4*)(Wfc + o * 512 + lane * 8);
                f32x4 w1 = *(const f32x4*)(Wfc + o * 512 + lane * 8 + 4);
                float s = hv[0] * w0.x + hv[1] * w0.y + hv[2] * w0.z + hv[3] * w0.w
                        + hv[4] * w1.x + hv[5] * w1.y + hv[6] * w1.z + hv[7] * w1.w;
#pragma unroll
                for (int sh = 32; sh >= 1; sh >>= 1) s += __shfl_down(s, sh);
                if (lane == 0)
                    out[bb * 7 + o] = s + bfc[o];
            }
        }
    }
}

extern "C" void kernel_launch(void* const* d_in, const int* in_sizes, int n_in,
                              void* d_out, int out_size, void* d_ws, size_t ws_size,
                              hipStream_t stream) {
    const int* tokens = (const int*)d_in[0];
    const float* emb  = (const float*)d_in[1];
    const float* Wih  = (const float*)d_in[2];
    const float* bih  = (const float*)d_in[3];
    const float* Whh  = (const float*)d_in[4];
    const float* bhh  = (const float*)d_in[5];
    const float* Wfc  = (const float*)d_in[6];
    const float* bfc  = (const float*)d_in[7];

    int* flags      = (int*)d_ws;                       // 1024 ints: per-wave flags
    ushort_t* hbuf  = (ushort_t*)((char*)d_ws + 4096);  // [2][256][512] bf16 = 512 KiB

    lstm_fused_kernel<<<dim3(128), dim3(512), 0, stream>>>(
        tokens, emb, Wih, bih, Whh, bhh, Wfc, bfc,
        (float*)d_out, flags, hbuf);
}